// Round 17
// baseline (23800.180 us; speedup 1.0000x reference)
//
#include <hip/hip_runtime.h>
#include <hip/hip_bf16.h>
#include <stdint.h>

typedef __attribute__((ext_vector_type(8))) short bf16x8;
typedef __attribute__((ext_vector_type(4))) float f32x4;
typedef __attribute__((address_space(1))) const void g_void;
typedef __attribute__((address_space(3))) void l_void;

#define NB 16
#define NC 256
#define NHW 4096
#define NT 72       // K-steps: 9 taps x 8 ci-blocks
#define SLOTB 8192  // per pipeline slot: IMG only (3 slots = 24KB)

// ---------- prep: x NCHW f32 -> xt2 [b][cib][4096 pix][32 ci] bf16 (+zp init) ----
__global__ __launch_bounds__(256) void prep_xt2(const float* __restrict__ x,
                                                __hip_bfloat16* __restrict__ xt2,
                                                float* __restrict__ zp) {
  __shared__ float tile[64][65];
  const int b = blockIdx.z;
  const int cb = blockIdx.y << 6;
  const int pb = blockIdx.x << 6;
  if (blockIdx.x == 0 && blockIdx.y == 0 && blockIdx.z == 0) {
#pragma unroll
    for (int q = 0; q < 8; ++q) zp[(q << 8) + threadIdx.x] = 0.f;
  }
  const float* xs = x + ((size_t)(b * NC + cb) << 12) + pb;
#pragma unroll
  for (int k = 0; k < 16; ++k) {
    int idx = threadIdx.x + (k << 8);
    int c = idx >> 6, p = idx & 63;
    tile[p][c] = xs[((size_t)c << 12) + p];
  }
  __syncthreads();
#pragma unroll
  for (int k = 0; k < 16; ++k) {
    int idx = threadIdx.x + (k << 8);
    int p = idx >> 6, c = idx & 63;
    int P = pb + p, C = cb + c;
    xt2[((size_t)(b * 8 + (C >> 5)) << 17) + ((size_t)P << 5) + (C & 31)] =
        __float2bfloat16(tile[p][c]);
  }
}

// ---------- prep: kernel [b][co][ci][3][3] f32 -> kt3 FRAGMENT-PACKED bf16 ----
// kt3[b][ct][tn][f 0..7][lane 0..63][e 0..7]: tn = cib*9+s; f = (co>>4)&7;
// lane = (co&15) + 16*((ci>>3)&3); e = ci&7. A wave's frag load is then
// global_load_dwordx4 at base + lane*16 — coalesced, no LDS needed.
__global__ __launch_bounds__(256) void prep_kt3(const float* __restrict__ kin,
                                                __hip_bfloat16* __restrict__ kt3) {
  const int bco = blockIdx.x;  // b*256 + co
  const int b = bco >> 8, co = bco & 255;
  const size_t base = (size_t)bco * 2304;
  const int ci = threadIdx.x;
  float v[9];
#pragma unroll
  for (int s = 0; s < 9; ++s) v[s] = kin[base + ci * 9 + s];
  const int cib = ci >> 5;
  const int ct = co >> 7;
  const int f = (co >> 4) & 7;
  const int ln = (co & 15) + (((ci >> 3) & 3) << 4);
  const int e = ci & 7;
#pragma unroll
  for (int s = 0; s < 9; ++s) {
    const size_t dst = ((size_t)((b * 2 + ct) * NT + cib * 9 + s) << 12) +
                       (f << 9) + (ln << 3) + e;
    kt3[dst] = __float2bfloat16(v[s]);
  }
}

// ---------- implicit-GEMM conv, 128x128 tile, kernel-direct-frags + image-LDS ----
// Phase p: [vmcnt(2); barrier] | 4 ds_read ifrg(p) | 4 global kf(p+1) loads |
//          cluster0 lgkm(3) | stage IMG(p+2) | clusters 1-3 lgkm(2/1/0).
// vmcnt(2) drains IMG(p)+KF(p) (keeps IMG(p+1) in flight); kernel frags ride
// in registers (double-buffered by phase parity), never touch LDS.
// PASS 1: A=image(M=pixel), B=kernel(N=co), out = ht2 bf16 [b][cib][pix][32] (relu)
// PASS 2: A=kernel(M=co), B=image(N=pixel), out = fp32 NCHW (x + .., relu)
template <int PASS>
__global__ __launch_bounds__(256, 3) void conv_gemm(
    const __hip_bfloat16* __restrict__ img2,  // [B][8][4096][32] (xt2 or ht2)
    const __hip_bfloat16* __restrict__ kt3,   // [B][2][72][8][64][8] frag-packed
    const float* __restrict__ xres,           // pass2 residual (NCHW f32)
    const __hip_bfloat16* __restrict__ zp,    // 8KB zeros
    void* __restrict__ outp) {
  __shared__ __align__(16) char L[3 * SLOTB];  // image tiles only

  const int tid = threadIdx.x;
  const int lane = tid & 63;
  const int wid = tid >> 6;  // 0..3
  const int wm = wid >> 1, wn = wid & 1;

  // XCD-affine: XCD x owns logical 128-block chunk = 2 complete samples
  const int orig = blockIdx.x;
  const int g = ((orig & 7) << 7) + (orig >> 3);
  const int b = g >> 6;
  const int t = g & 63;
  const int ptile = t >> 1;
  const int ct = t & 1;
  const int pbase = ptile << 7;

  const char* xb = (const char*)img2 + ((size_t)b << 21);  // sample base (bytes)
  const char* ktb = (const char*)kt3 + (((size_t)(b * 2 + ct) * NT) << 13);
  const char* zpb = (const char*)zp;
  const char* zpL = zpb + (lane << 4);

  // image staging lane geometry (pre-swizzled source chunk)
  const int srow = lane >> 2;
  const int sch = (lane & 3) ^ ((srow >> 1) & 3);

  // persistent image stage address (tap added per step; bumped at cib cross)
  const char* aCur[2];
#pragma unroll
  for (int i = 0; i < 2; ++i) {
    const int grp = (i << 2) + wid;
    aCur[i] = xb + ((size_t)((pbase + (grp << 4) + srow) << 6)) + (sch << 4);
  }

  // image fragment LDS read offsets (swizzled)
  const int wI = (PASS == 1) ? wm : wn;  // image-side wave coord
  const int wK = (PASS == 1) ? wn : wm;  // kernel-side wave coord
  int ioff[4];
#pragma unroll
  for (int f = 0; f < 4; ++f) {
    const int ir = (wI << 6) + (f << 4) + (lane & 15);
    ioff[f] = (ir << 6) + ((((lane >> 4) ^ ((ir >> 1) & 3))) << 4);
  }
  // kernel frag pointer: frag idx = wK*4+f, advance 8KB per phase
  const char* kfb = ktb + ((wK << 2) << 10) + (lane << 4);
  const bool killlo = (lane & 15) == 0;
  const bool killhi = (lane & 15) == 15;
  const bf16x8 z8 = {0, 0, 0, 0, 0, 0, 0, 0};

  f32x4 acc[4][4];
#pragma unroll
  for (int i = 0; i < 4; ++i)
#pragma unroll
    for (int j = 0; j < 4; ++j) acc[i][j] = (f32x4){0.f, 0.f, 0.f, 0.f};

  bf16x8 kf[2][4];  // kernel frags, phase-parity double-buffered (registers)

  // image tile stage: contiguous 8KB at tap offset; per-instr uniform h-redirect
  auto stageA = [&](int sl2, int dh2, int dw2, bool dmy) {
    const int TAP = (dh2 * 64 + dw2) * 64;
#pragma unroll
    for (int i = 0; i < 2; ++i) {
      const int grp = (i << 2) + wid;
      const bool ok = !dmy && ((unsigned)((ptile << 1) + i + dh2) < 64u);
      const char* srcA = ok ? aCur[i] + TAP : zpL;
      __builtin_amdgcn_global_load_lds((g_void*)srcA,
                                       (l_void*)(L + sl2 * SLOTB + (grp << 10)), 16, 0, 0);
    }
  };
  auto loadKF = [&](int par) {  // 4 coalesced frag loads from kfb, then advance
#pragma unroll
    for (int f = 0; f < 4; ++f) kf[par][f] = *(const bf16x8*)(kfb + (f << 10));
    kfb += 8192;
  };

  // prologue: IMG(0)x2, KF(0)x4, IMG(1)x2  (8 VMEM in flight)
  stageA(0, -1, -1, false);  // tile 0 = tap (-1,-1)
  loadKF(0);
  stageA(1, -1, 0, false);   // tile 1 = tap (-1,0)

#pragma unroll 1
  for (int c9 = 0; c9 < 8; ++c9) {
#pragma unroll
    for (int s = 0; s < 9; ++s) {  // s compile-time; slot = s%3 (9%3==0)
      const int par = s & 1;       // 9 odd: parity alternates via (c9*9+s)&1...
      const int parx = (c9 & 1) ^ par;  // true phase parity (c9*9+s)&1
      const int dwc = s % 3 - 1;

      // top rendezvous: drains IMG(kk)+KF(kk) (6 oldest), keeps IMG(kk+1)
      asm volatile("s_waitcnt vmcnt(2)" ::: "memory");
      __builtin_amdgcn_s_barrier();
      __builtin_amdgcn_sched_barrier(0);

      // 4 image frag ds_reads (slot s%3)
      const char* As = L + (s % 3) * SLOTB;
      bf16x8 ifr[4];
#pragma unroll
      for (int f = 0; f < 4; ++f) ifr[f] = *(const bf16x8*)(As + ioff[f]);
      __builtin_amdgcn_sched_barrier(0);

      // kernel frags for phase kk+1 (retire by next top's vmcnt(2))
      loadKF(parx ^ 1);
      __builtin_amdgcn_sched_barrier(0);

      // ---- cluster 0 (image frag 0) ----
      asm volatile("s_waitcnt lgkmcnt(3)" ::: "memory");
      __builtin_amdgcn_sched_barrier(0);
      if (dwc == -1) ifr[0] = killlo ? z8 : ifr[0];
      __builtin_amdgcn_s_setprio(1);
#pragma unroll
      for (int q = 0; q < 4; ++q) {
        if (PASS == 1)
          acc[0][q] = __builtin_amdgcn_mfma_f32_16x16x32_bf16(ifr[0], kf[parx][q], acc[0][q], 0, 0, 0);
        else
          acc[q][0] = __builtin_amdgcn_mfma_f32_16x16x32_bf16(kf[parx][q], ifr[0], acc[q][0], 0, 0, 0);
      }
      __builtin_amdgcn_sched_barrier(0);

      // stage IMG(kk+2) under MFMA shadow; bump image base at cib cross
      {
        if (s == 7) {
          aCur[0] += 262144;
          aCur[1] += 262144;
        }
        const int s2 = (s + 2) % 9;
        const bool dmy = (c9 == 7) && (s >= 7);
        stageA((s + 2) % 3, s2 / 3 - 1, s2 % 3 - 1, dmy);
      }
      __builtin_amdgcn_sched_barrier(0);

      // ---- clusters 1..3 ----
      asm volatile("s_waitcnt lgkmcnt(2)" ::: "memory");
      __builtin_amdgcn_sched_barrier(0);
#pragma unroll
      for (int q = 0; q < 4; ++q) {
        if (PASS == 1)
          acc[1][q] = __builtin_amdgcn_mfma_f32_16x16x32_bf16(ifr[1], kf[parx][q], acc[1][q], 0, 0, 0);
        else
          acc[q][1] = __builtin_amdgcn_mfma_f32_16x16x32_bf16(kf[parx][q], ifr[1], acc[q][1], 0, 0, 0);
      }
      __builtin_amdgcn_sched_barrier(0);
      asm volatile("s_waitcnt lgkmcnt(1)" ::: "memory");
      __builtin_amdgcn_sched_barrier(0);
#pragma unroll
      for (int q = 0; q < 4; ++q) {
        if (PASS == 1)
          acc[2][q] = __builtin_amdgcn_mfma_f32_16x16x32_bf16(ifr[2], kf[parx][q], acc[2][q], 0, 0, 0);
        else
          acc[q][2] = __builtin_amdgcn_mfma_f32_16x16x32_bf16(kf[parx][q], ifr[2], acc[q][2], 0, 0, 0);
      }
      __builtin_amdgcn_sched_barrier(0);
      asm volatile("s_waitcnt lgkmcnt(0)" ::: "memory");
      __builtin_amdgcn_sched_barrier(0);
      if (dwc == 1) ifr[3] = killhi ? z8 : ifr[3];
#pragma unroll
      for (int q = 0; q < 4; ++q) {
        if (PASS == 1)
          acc[3][q] = __builtin_amdgcn_mfma_f32_16x16x32_bf16(ifr[3], kf[parx][q], acc[3][q], 0, 0, 0);
        else
          acc[q][3] = __builtin_amdgcn_mfma_f32_16x16x32_bf16(kf[parx][q], ifr[3], acc[q][3], 0, 0, 0);
      }
      __builtin_amdgcn_s_setprio(0);
      __builtin_amdgcn_sched_barrier(0);
    }
  }
  // drain tail dummy DMA + unused KF loads
  asm volatile("s_waitcnt vmcnt(0)" ::: "memory");
  __builtin_amdgcn_sched_barrier(0);

  const int lg = lane >> 4;
  const int ln = lane & 15;
  if (PASS == 1) {
    __hip_bfloat16* ho = (__hip_bfloat16*)outp;  // ht2 layout [b][cib][pix][32]
#pragma unroll
    for (int i = 0; i < 4; ++i)
#pragma unroll
      for (int j = 0; j < 4; ++j)
#pragma unroll
        for (int r = 0; r < 4; ++r) {
          int pixel = pbase + (wm << 6) + (i << 4) + (lg << 2) + r;
          int co = (ct << 7) + (wn << 6) + (j << 4) + ln;
          float v = acc[i][j][r];
          v = v > 0.f ? v : 0.f;
          ho[((size_t)(b * 8 + (co >> 5)) << 17) + ((size_t)pixel << 5) + (co & 31)] =
              __float2bfloat16(v);
        }
  } else {
    float* oo = (float*)outp;
#pragma unroll
    for (int i = 0; i < 4; ++i)
#pragma unroll
      for (int j = 0; j < 4; ++j)
#pragma unroll
        for (int r = 0; r < 4; ++r) {
          int co = (ct << 7) + (wm << 6) + (i << 4) + (lg << 2) + r;
          int pixel = pbase + (wn << 6) + (j << 4) + ln;
          size_t idx = ((size_t)(b * NC + co) << 12) + pixel;
          float v = acc[i][j][r] + xres[idx];
          oo[idx] = v > 0.f ? v : 0.f;
        }
  }
}

extern "C" void kernel_launch(void* const* d_in, const int* in_sizes, int n_in,
                              void* d_out, int out_size, void* d_ws, size_t ws_size,
                              hipStream_t stream) {
  const float* x = (const float*)d_in[0];
  const float* k1 = (const float*)d_in[1];
  const float* k2 = (const float*)d_in[2];

  // ws: pad 256B | xt2 (33.6MB) | ht2 (33.6MB) | kt3 (18.9MB, reused) | zp (8KB)
  char* w = (char*)d_ws;
  __hip_bfloat16* xt2 = (__hip_bfloat16*)(w + 256);
  __hip_bfloat16* ht2 = xt2 + (size_t)NB * 8 * NHW * 32;
  __hip_bfloat16* kt3 = ht2 + (size_t)NB * 8 * NHW * 32;
  float* zp = (float*)(kt3 + (size_t)NB * 2 * NT * 4096);

  prep_xt2<<<dim3(64, 4, NB), 256, 0, stream>>>(x, xt2, zp);
  prep_kt3<<<dim3(NB * NC), 256, 0, stream>>>(k1, kt3);
  conv_gemm<1><<<dim3(1024), 256, 0, stream>>>(xt2, kt3, nullptr,
                                               (const __hip_bfloat16*)zp, (void*)ht2);
  prep_kt3<<<dim3(NB * NC), 256, 0, stream>>>(k2, kt3);
  conv_gemm<2><<<dim3(1024), 256, 0, stream>>>(ht2, kt3, x,
                                               (const __hip_bfloat16*)zp, d_out);
}

// Round 18
// 234.773 us; speedup vs baseline: 101.3753x; 101.3753x over previous
//
#include <hip/hip_runtime.h>
#include <hip/hip_bf16.h>
#include <stdint.h>

typedef __attribute__((ext_vector_type(8))) short bf16x8;
typedef __attribute__((ext_vector_type(4))) float f32x4;
typedef __attribute__((address_space(1))) const void g_void;
typedef __attribute__((address_space(3))) void l_void;

#define NB 16
#define NC 256
#define NHW 4096
#define NT 72       // K-steps: 9 taps x 8 ci-blocks
#define SLOTB 8192  // per pipeline slot: IMG only (3 slots = 24KB)

// ---------- prep: x NCHW f32 -> xt2 [b][cib][4096 pix][32 ci] bf16 (+zp init) ----
__global__ __launch_bounds__(256) void prep_xt2(const float* __restrict__ x,
                                                __hip_bfloat16* __restrict__ xt2,
                                                float* __restrict__ zp) {
  __shared__ float tile[64][65];
  const int b = blockIdx.z;
  const int cb = blockIdx.y << 6;
  const int pb = blockIdx.x << 6;
  if (blockIdx.x == 0 && blockIdx.y == 0 && blockIdx.z == 0) {
#pragma unroll
    for (int q = 0; q < 8; ++q) zp[(q << 8) + threadIdx.x] = 0.f;
  }
  const float* xs = x + ((size_t)(b * NC + cb) << 12) + pb;
#pragma unroll
  for (int k = 0; k < 16; ++k) {
    int idx = threadIdx.x + (k << 8);
    int c = idx >> 6, p = idx & 63;
    tile[p][c] = xs[((size_t)c << 12) + p];
  }
  __syncthreads();
#pragma unroll
  for (int k = 0; k < 16; ++k) {
    int idx = threadIdx.x + (k << 8);
    int p = idx >> 6, c = idx & 63;
    int P = pb + p, C = cb + c;
    xt2[((size_t)(b * 8 + (C >> 5)) << 17) + ((size_t)P << 5) + (C & 31)] =
        __float2bfloat16(tile[p][c]);
  }
}

// ---------- prep: kernel [b][co][ci][3][3] f32 -> kt3 FRAGMENT-PACKED bf16 ----
// kt3[b][ct][tn][f 0..7][lane 0..63][e 0..7]: tn = cib*9+s; f = (co>>4)&7;
// lane = (co&15) + 16*((ci>>3)&3); e = ci&7. A wave's frag load is then
// global_load_dwordx4 at base + lane*16 — coalesced, no LDS needed.
__global__ __launch_bounds__(256) void prep_kt3(const float* __restrict__ kin,
                                                __hip_bfloat16* __restrict__ kt3) {
  const int bco = blockIdx.x;  // b*256 + co
  const int b = bco >> 8, co = bco & 255;
  const size_t base = (size_t)bco * 2304;
  const int ci = threadIdx.x;
  float v[9];
#pragma unroll
  for (int s = 0; s < 9; ++s) v[s] = kin[base + ci * 9 + s];
  const int cib = ci >> 5;
  const int ct = co >> 7;
  const int f = (co >> 4) & 7;
  const int ln = (co & 15) + (((ci >> 3) & 3) << 4);
  const int e = ci & 7;
#pragma unroll
  for (int s = 0; s < 9; ++s) {
    const size_t dst = ((size_t)((b * 2 + ct) * NT + cib * 9 + s) << 12) +
                       (f << 9) + (ln << 3) + e;
    kt3[dst] = __float2bfloat16(v[s]);
  }
}

// ---------- implicit-GEMM conv, 128x128 tile, kernel-direct-frags + image-LDS ----
// Phase p: [vmcnt(2); barrier] | 4 ds_read ifrg(p) | 4 global kf(p+1) loads |
//          cluster0 lgkm(3) | stage IMG(p+2) | clusters 1-3 lgkm(2/1/0).
// 18-step unroll => kf parity u&1, slot u%3, tap u%9 ALL compile-time (rule #20:
// runtime-indexed reg arrays go to scratch — that was round 17's 150x regression).
// PASS 1: A=image(M=pixel), B=kernel(N=co), out = ht2 bf16 [b][cib][pix][32] (relu)
// PASS 2: A=kernel(M=co), B=image(N=pixel), out = fp32 NCHW (x + .., relu)
template <int PASS>
__global__ __launch_bounds__(256, 3) void conv_gemm(
    const __hip_bfloat16* __restrict__ img2,  // [B][8][4096][32] (xt2 or ht2)
    const __hip_bfloat16* __restrict__ kt3,   // [B][2][72][8][64][8] frag-packed
    const float* __restrict__ xres,           // pass2 residual (NCHW f32)
    const __hip_bfloat16* __restrict__ zp,    // 8KB zeros
    void* __restrict__ outp) {
  __shared__ __align__(16) char L[3 * SLOTB];  // image tiles only

  const int tid = threadIdx.x;
  const int lane = tid & 63;
  const int wid = tid >> 6;  // 0..3
  const int wm = wid >> 1, wn = wid & 1;

  // XCD-affine: XCD x owns logical 128-block chunk = 2 complete samples
  const int orig = blockIdx.x;
  const int g = ((orig & 7) << 7) + (orig >> 3);
  const int b = g >> 6;
  const int t = g & 63;
  const int ptile = t >> 1;
  const int ct = t & 1;
  const int pbase = ptile << 7;

  const char* xb = (const char*)img2 + ((size_t)b << 21);  // sample base (bytes)
  const char* ktb = (const char*)kt3 + (((size_t)(b * 2 + ct) * NT) << 13);
  const char* zpb = (const char*)zp;
  const char* zpL = zpb + (lane << 4);

  // image staging lane geometry (pre-swizzled source chunk)
  const int srow = lane >> 2;
  const int sch = (lane & 3) ^ ((srow >> 1) & 3);

  // persistent image stage address (tap added per step; bumped at cib cross)
  const char* aCur[2];
#pragma unroll
  for (int i = 0; i < 2; ++i) {
    const int grp = (i << 2) + wid;
    aCur[i] = xb + ((size_t)((pbase + (grp << 4) + srow) << 6)) + (sch << 4);
  }

  // image fragment LDS read offsets (swizzled)
  const int wI = (PASS == 1) ? wm : wn;  // image-side wave coord
  const int wK = (PASS == 1) ? wn : wm;  // kernel-side wave coord
  int ioff[4];
#pragma unroll
  for (int f = 0; f < 4; ++f) {
    const int ir = (wI << 6) + (f << 4) + (lane & 15);
    ioff[f] = (ir << 6) + ((((lane >> 4) ^ ((ir >> 1) & 3))) << 4);
  }
  // kernel frag pointer: frag idx = wK*4+f, advance 8KB per phase
  const char* kfb = ktb + ((wK << 2) << 10) + (lane << 4);
  const bool killlo = (lane & 15) == 0;
  const bool killhi = (lane & 15) == 15;
  const bf16x8 z8 = {0, 0, 0, 0, 0, 0, 0, 0};

  f32x4 acc[4][4];
#pragma unroll
  for (int i = 0; i < 4; ++i)
#pragma unroll
    for (int j = 0; j < 4; ++j) acc[i][j] = (f32x4){0.f, 0.f, 0.f, 0.f};

  bf16x8 kf0[4], kf1[4];  // kernel frags, STATIC phase-parity double buffer

  // image tile stage: contiguous 8KB at tap offset; per-instr uniform h-redirect
  auto stageA = [&](int sl2, int dh2, int dw2, bool dmy) {
    const int TAP = (dh2 * 64 + dw2) * 64;
#pragma unroll
    for (int i = 0; i < 2; ++i) {
      const int grp = (i << 2) + wid;
      const bool ok = !dmy && ((unsigned)((ptile << 1) + i + dh2) < 64u);
      const char* srcA = ok ? aCur[i] + TAP : zpL;
      __builtin_amdgcn_global_load_lds((g_void*)srcA,
                                       (l_void*)(L + sl2 * SLOTB + (grp << 10)), 16, 0, 0);
    }
  };

  // prologue: IMG(0)x2, KF(0)->kf0 x4, IMG(1)x2  (8 VMEM in flight)
  stageA(0, -1, -1, false);  // tile 0 = tap (-1,-1)
#pragma unroll
  for (int f = 0; f < 4; ++f) kf0[f] = *(const bf16x8*)(kfb + (f << 10));
  kfb += 8192;
  stageA(1, -1, 0, false);   // tile 1 = tap (-1,0)

#pragma unroll 1
  for (int c18 = 0; c18 < 4; ++c18) {
#pragma unroll
    for (int u = 0; u < 18; ++u) {  // p = c18*18+u; u&1, u%3, u%9 compile-time
      const int s = u % 9;
      const int dwc = s % 3 - 1;
      bf16x8* kcur = (u & 1) ? kf1 : kf0;
      bf16x8* knxt = (u & 1) ? kf0 : kf1;

      // top rendezvous: drains IMG(kk)+KF(kk) (6 oldest), keeps IMG(kk+1)
      asm volatile("s_waitcnt vmcnt(2)" ::: "memory");
      __builtin_amdgcn_s_barrier();
      __builtin_amdgcn_sched_barrier(0);

      // 4 image frag ds_reads (slot u%3)
      const char* As = L + (u % 3) * SLOTB;
      bf16x8 ifr[4];
#pragma unroll
      for (int f = 0; f < 4; ++f) ifr[f] = *(const bf16x8*)(As + ioff[f]);
      __builtin_amdgcn_sched_barrier(0);

      // kernel frags for phase kk+1 (retire by next top's vmcnt(2))
#pragma unroll
      for (int f = 0; f < 4; ++f) knxt[f] = *(const bf16x8*)(kfb + (f << 10));
      kfb += 8192;
      __builtin_amdgcn_sched_barrier(0);

      // ---- cluster 0 (image frag 0) ----
      asm volatile("s_waitcnt lgkmcnt(3)" ::: "memory");
      __builtin_amdgcn_sched_barrier(0);
      if (dwc == -1) ifr[0] = killlo ? z8 : ifr[0];
      __builtin_amdgcn_s_setprio(1);
#pragma unroll
      for (int q = 0; q < 4; ++q) {
        if (PASS == 1)
          acc[0][q] = __builtin_amdgcn_mfma_f32_16x16x32_bf16(ifr[0], kcur[q], acc[0][q], 0, 0, 0);
        else
          acc[q][0] = __builtin_amdgcn_mfma_f32_16x16x32_bf16(kcur[q], ifr[0], acc[q][0], 0, 0, 0);
      }
      __builtin_amdgcn_sched_barrier(0);

      // stage IMG(kk+2) under MFMA shadow; bump image base at cib cross
      {
        if (s == 7) {
          aCur[0] += 262144;
          aCur[1] += 262144;
        }
        const int s2 = (s + 2) % 9;
        const bool dmy = (c18 == 3) && (u >= 16);  // tn = p+2 >= 72
        stageA((u + 2) % 3, s2 / 3 - 1, s2 % 3 - 1, dmy);
      }
      __builtin_amdgcn_sched_barrier(0);

      // ---- clusters 1..3 ----
      asm volatile("s_waitcnt lgkmcnt(2)" ::: "memory");
      __builtin_amdgcn_sched_barrier(0);
#pragma unroll
      for (int q = 0; q < 4; ++q) {
        if (PASS == 1)
          acc[1][q] = __builtin_amdgcn_mfma_f32_16x16x32_bf16(ifr[1], kcur[q], acc[1][q], 0, 0, 0);
        else
          acc[q][1] = __builtin_amdgcn_mfma_f32_16x16x32_bf16(kcur[q], ifr[1], acc[q][1], 0, 0, 0);
      }
      __builtin_amdgcn_sched_barrier(0);
      asm volatile("s_waitcnt lgkmcnt(1)" ::: "memory");
      __builtin_amdgcn_sched_barrier(0);
#pragma unroll
      for (int q = 0; q < 4; ++q) {
        if (PASS == 1)
          acc[2][q] = __builtin_amdgcn_mfma_f32_16x16x32_bf16(ifr[2], kcur[q], acc[2][q], 0, 0, 0);
        else
          acc[q][2] = __builtin_amdgcn_mfma_f32_16x16x32_bf16(kcur[q], ifr[2], acc[q][2], 0, 0, 0);
      }
      __builtin_amdgcn_sched_barrier(0);
      asm volatile("s_waitcnt lgkmcnt(0)" ::: "memory");
      __builtin_amdgcn_sched_barrier(0);
      if (dwc == 1) ifr[3] = killhi ? z8 : ifr[3];
#pragma unroll
      for (int q = 0; q < 4; ++q) {
        if (PASS == 1)
          acc[3][q] = __builtin_amdgcn_mfma_f32_16x16x32_bf16(ifr[3], kcur[q], acc[3][q], 0, 0, 0);
        else
          acc[q][3] = __builtin_amdgcn_mfma_f32_16x16x32_bf16(kcur[q], ifr[3], acc[q][3], 0, 0, 0);
      }
      __builtin_amdgcn_s_setprio(0);
      __builtin_amdgcn_sched_barrier(0);
    }
  }
  // drain tail dummy DMA + unused KF loads
  asm volatile("s_waitcnt vmcnt(0)" ::: "memory");
  __builtin_amdgcn_sched_barrier(0);

  const int lg = lane >> 4;
  const int ln = lane & 15;
  if (PASS == 1) {
    __hip_bfloat16* ho = (__hip_bfloat16*)outp;  // ht2 layout [b][cib][pix][32]
#pragma unroll
    for (int i = 0; i < 4; ++i)
#pragma unroll
      for (int j = 0; j < 4; ++j)
#pragma unroll
        for (int r = 0; r < 4; ++r) {
          int pixel = pbase + (wm << 6) + (i << 4) + (lg << 2) + r;
          int co = (ct << 7) + (wn << 6) + (j << 4) + ln;
          float v = acc[i][j][r];
          v = v > 0.f ? v : 0.f;
          ho[((size_t)(b * 8 + (co >> 5)) << 17) + ((size_t)pixel << 5) + (co & 31)] =
              __float2bfloat16(v);
        }
  } else {
    float* oo = (float*)outp;
#pragma unroll
    for (int i = 0; i < 4; ++i)
#pragma unroll
      for (int j = 0; j < 4; ++j)
#pragma unroll
        for (int r = 0; r < 4; ++r) {
          int co = (ct << 7) + (wm << 6) + (i << 4) + (lg << 2) + r;
          int pixel = pbase + (wn << 6) + (j << 4) + ln;
          size_t idx = ((size_t)(b * NC + co) << 12) + pixel;
          float v = acc[i][j][r] + xres[idx];
          oo[idx] = v > 0.f ? v : 0.f;
        }
  }
}

extern "C" void kernel_launch(void* const* d_in, const int* in_sizes, int n_in,
                              void* d_out, int out_size, void* d_ws, size_t ws_size,
                              hipStream_t stream) {
  const float* x = (const float*)d_in[0];
  const float* k1 = (const float*)d_in[1];
  const float* k2 = (const float*)d_in[2];

  // ws: pad 256B | xt2 (33.6MB) | ht2 (33.6MB) | kt3 (18.9MB, reused) | zp (8KB)
  char* w = (char*)d_ws;
  __hip_bfloat16* xt2 = (__hip_bfloat16*)(w + 256);
  __hip_bfloat16* ht2 = xt2 + (size_t)NB * 8 * NHW * 32;
  __hip_bfloat16* kt3 = ht2 + (size_t)NB * 8 * NHW * 32;
  float* zp = (float*)(kt3 + (size_t)NB * 2 * NT * 4096);

  prep_xt2<<<dim3(64, 4, NB), 256, 0, stream>>>(x, xt2, zp);
  prep_kt3<<<dim3(NB * NC), 256, 0, stream>>>(k1, kt3);
  conv_gemm<1><<<dim3(1024), 256, 0, stream>>>(xt2, kt3, nullptr,
                                               (const __hip_bfloat16*)zp, (void*)ht2);
  prep_kt3<<<dim3(NB * NC), 256, 0, stream>>>(k2, kt3);
  conv_gemm<2><<<dim3(1024), 256, 0, stream>>>(ht2, kt3, x,
                                               (const __hip_bfloat16*)zp, d_out);
}

// Round 19
// 179.791 us; speedup vs baseline: 132.3772x; 1.3058x over previous
//
#include <hip/hip_runtime.h>
#include <hip/hip_bf16.h>
#include <stdint.h>

typedef __attribute__((ext_vector_type(8))) short bf16x8;
typedef __attribute__((ext_vector_type(4))) float f32x4;
typedef __attribute__((address_space(1))) const void g_void;
typedef __attribute__((address_space(3))) void l_void;

#define NB 16
#define NC 256
#define NHW 4096
#define NT 72        // K-steps: 9 taps x 8 ci-blocks
#define SLOTB 16384  // per pipeline slot: IMG 8KB + KER 8KB (3 slots = 48KB)

// ---------- prep device bodies ----------
__device__ __forceinline__ void do_xt2(int bx, const float* __restrict__ x,
                                       __hip_bfloat16* __restrict__ xt2,
                                       float* __restrict__ zp) {
  __shared__ float tile[64][65];
  const int b = bx >> 8;
  const int cb = ((bx >> 6) & 3) << 6;
  const int pb = (bx & 63) << 6;
  if (bx == 0) {
#pragma unroll
    for (int q = 0; q < 8; ++q) zp[(q << 8) + threadIdx.x] = 0.f;
  }
  const float* xs = x + ((size_t)(b * NC + cb) << 12) + pb;
#pragma unroll
  for (int k = 0; k < 16; ++k) {
    int idx = threadIdx.x + (k << 8);
    int c = idx >> 6, p = idx & 63;
    tile[p][c] = xs[((size_t)c << 12) + p];
  }
  __syncthreads();
#pragma unroll
  for (int k = 0; k < 16; ++k) {
    int idx = threadIdx.x + (k << 8);
    int p = idx >> 6, c = idx & 63;
    int P = pb + p, C = cb + c;
    xt2[((size_t)(b * 8 + (C >> 5)) << 17) + ((size_t)P << 5) + (C & 31)] =
        __float2bfloat16(tile[p][c]);
  }
}

// kernel [b][co][ci][3][3] f32 -> kt2 [b][ct][tn][128][32] bf16, tn = cib*9+s,
// chunk pre-swizzled: stored-slot = chunk ^ ((row>>1)&3)
__device__ __forceinline__ void do_kt2(int bco, const float* __restrict__ kin,
                                       __hip_bfloat16* __restrict__ kt2) {
  const int b = bco >> 8, co = bco & 255;
  const size_t base = (size_t)bco * 2304;
  const int ci = threadIdx.x;
  float v[9];
#pragma unroll
  for (int s = 0; s < 9; ++s) v[s] = kin[base + ci * 9 + s];
  const int cib = ci >> 5, chunk = (ci >> 3) & 3, e = ci & 7;
  const int row = co & 127, ct = co >> 7;
  const int sc = chunk ^ ((row >> 1) & 3);
#pragma unroll
  for (int s = 0; s < 9; ++s) {
    const size_t dst = (((size_t)(b * 2 + ct) * NT + (cib * 9 + s)) << 12) +
                       (row << 5) + (sc << 3) + e;
    kt2[dst] = __float2bfloat16(v[s]);
  }
}

// fused prep: blocks [0,4096) xt2+zp; [4096,8192) kt2(k1); [8192,12288) kt2(k2)
__global__ __launch_bounds__(256) void prep_all(const float* __restrict__ x,
                                                __hip_bfloat16* __restrict__ xt2,
                                                float* __restrict__ zp,
                                                const float* __restrict__ k1,
                                                __hip_bfloat16* __restrict__ kt2a,
                                                const float* __restrict__ k2,
                                                __hip_bfloat16* __restrict__ kt2b) {
  const int bx = blockIdx.x;
  if (bx < 4096)
    do_xt2(bx, x, xt2, zp);
  else if (bx < 8192)
    do_kt2(bx - 4096, k1, kt2a);
  else
    do_kt2(bx - 8192, k2, kt2b);
}

// standalone fallbacks (small-ws path)
__global__ __launch_bounds__(256) void prep_xt2(const float* __restrict__ x,
                                                __hip_bfloat16* __restrict__ xt2,
                                                float* __restrict__ zp) {
  do_xt2(blockIdx.x, x, xt2, zp);
}
__global__ __launch_bounds__(256) void prep_kt2(const float* __restrict__ kin,
                                                __hip_bfloat16* __restrict__ kt2) {
  do_kt2(blockIdx.x, kin, kt2);
}

// ---------- implicit-GEMM conv, 128x128 tile, 3 blocks/CU, partial-lgkm clusters ----
// (round-16 verified structure: 77.6 us/conv, MfmaUtil 42.6%, 0 conflicts)
// Phase kk: [vmcnt(4); barrier] | 8 ds_read (b0-3, a0-3) | lgkm(3) cluster0 |
//           stage tile kk+2 | lgkm(2) c1 | lgkm(1) c2 | lgkm(0) c3.
// PASS 1: A=image(M=pixel), B=kernel(N=co), out = ht2 bf16 [b][cib][pix][32] (relu)
// PASS 2: A=kernel(M=co), B=image(N=pixel), out = fp32 NCHW (x + .., relu)
template <int PASS>
__global__ __launch_bounds__(256, 3) void conv_gemm(
    const __hip_bfloat16* __restrict__ img2,  // [B][8][4096][32] (xt2 or ht2)
    const __hip_bfloat16* __restrict__ kt2,   // [B][2][72][128][32] pre-swizzled
    const float* __restrict__ xres,           // pass2 residual (NCHW f32)
    const __hip_bfloat16* __restrict__ zp,    // 8KB zeros
    void* __restrict__ outp) {
  __shared__ __align__(16) char L[3 * SLOTB];  // slot: [IMG 8KB | KER 8KB]

  const int tid = threadIdx.x;
  const int lane = tid & 63;
  const int wid = tid >> 6;  // 0..3
  const int wm = wid >> 1, wn = wid & 1;

  // XCD-affine: XCD x owns logical 128-block chunk = 2 complete samples
  const int orig = blockIdx.x;
  const int g = ((orig & 7) << 7) + (orig >> 3);
  const int b = g >> 6;
  const int t = g & 63;
  const int ptile = t >> 1;
  const int ct = t & 1;
  const int pbase = ptile << 7;

  const char* xb = (const char*)img2 + ((size_t)b << 21);  // sample base (bytes)
  const char* ktb = (const char*)kt2 + (((size_t)(b * 2 + ct) * NT) << 13);
  const char* zpb = (const char*)zp;
  const char* zpL = zpb + (lane << 4);

  // staging lane geometry: instr covers 16 rows; lane -> row +(lane>>2),
  // HW LDS slot lane&3; source chunk pre-swizzled: sch = (lane&3) ^ ((srow>>1)&3)
  const int srow = lane >> 2;
  const int sch = (lane & 3) ^ ((srow >> 1) & 3);

  // persistent stage addresses (incremental)
  const char* aCur[2];  // image: cib base + per-row lane address (tap added per step)
  const char* kAddr[2]; // kernel: tile pointer, += 8KB per phase
#pragma unroll
  for (int i = 0; i < 2; ++i) {
    const int grp = (i << 2) + wid;
    aCur[i] = xb + ((size_t)((pbase + (grp << 4) + srow) << 6)) + (sch << 4);
    kAddr[i] = ktb + (grp << 10) + (lane << 4);
  }

  // fragment read offsets (bytes)
  const int wI = (PASS == 1) ? wm : wn;  // image-side wave coord
  const int wK = (PASS == 1) ? wn : wm;  // kernel-side wave coord
  int ioff[4], koff[4];
#pragma unroll
  for (int f = 0; f < 4; ++f) {
    const int ir = (wI << 6) + (f << 4) + (lane & 15);
    ioff[f] = (ir << 6) + ((((lane >> 4) ^ ((ir >> 1) & 3))) << 4);
    const int kr = (wK << 6) + (f << 4) + (lane & 15);
    koff[f] = (kr << 6) + ((((lane >> 4) ^ ((kr >> 1) & 3))) << 4);
  }
  const int* aoffP = (PASS == 1) ? ioff : koff;  // M-side (cluster operand)
  const int* boffP = (PASS == 1) ? koff : ioff;  // N-side (shared operand)
  const bool killlo = (lane & 15) == 0;
  const bool killhi = (lane & 15) == 15;
  const bf16x8 z8 = {0, 0, 0, 0, 0, 0, 0, 0};

  f32x4 acc[4][4];
#pragma unroll
  for (int i = 0; i < 4; ++i)
#pragma unroll
    for (int j = 0; j < 4; ++j) acc[i][j] = (f32x4){0.f, 0.f, 0.f, 0.f};

  // stage tile tn (image tap s2 + kernel) into slot sl2; dmy -> zero page
  auto stage = [&](int sl2, int s2, bool dmy) {
    const int dh2 = s2 / 3 - 1, dw2 = s2 % 3 - 1;
    const int TAP = (dh2 * 64 + dw2) * 64;
#pragma unroll
    for (int i = 0; i < 2; ++i) {
      const int grp = (i << 2) + wid;
      const bool ok = !dmy && ((unsigned)((ptile << 1) + i + dh2) < 64u);
      const char* srcA = ok ? aCur[i] + TAP : zpL;
      __builtin_amdgcn_global_load_lds((g_void*)srcA,
                                       (l_void*)(L + sl2 * SLOTB + (grp << 10)), 16, 0, 0);
      const char* srcK = !dmy ? kAddr[i] : zpL;
      __builtin_amdgcn_global_load_lds(
          (g_void*)srcK, (l_void*)(L + sl2 * SLOTB + 8192 + (grp << 10)), 16, 0, 0);
      kAddr[i] += 8192;
    }
  };

  // prologue: tile 0 (tap 0) -> slot 0, tile 1 (tap 1) -> slot 1
  stage(0, 0, false);
  stage(1, 1, false);

#pragma unroll 1
  for (int c9 = 0; c9 < 8; ++c9) {
#pragma unroll
    for (int s = 0; s < 9; ++s) {  // s compile-time; slot = s%3 (9%3==0)
      const int sl = s % 3;
      const int dwc = s % 3 - 1;  // current tap dw (w-edge kills)

      // top rendezvous: tile kk resident (2-phase DMA lead), cross-wave via barrier
      asm volatile("s_waitcnt vmcnt(4)" ::: "memory");
      __builtin_amdgcn_s_barrier();
      __builtin_amdgcn_sched_barrier(0);

      // 8 ds_reads in pinned order: b0..b3 (shared N-side), a0..a3 (M-side)
      const char* Rb = L + sl * SLOTB + ((PASS == 1) ? 8192 : 0);
      const char* Ra = L + sl * SLOTB + ((PASS == 1) ? 0 : 8192);
      bf16x8 bfr[4], afr[4];
#pragma unroll
      for (int j = 0; j < 4; ++j) bfr[j] = *(const bf16x8*)(Rb + boffP[j]);
#pragma unroll
      for (int f = 0; f < 4; ++f) afr[f] = *(const bf16x8*)(Ra + aoffP[f]);
      __builtin_amdgcn_sched_barrier(0);

      // ---- cluster 0: needs b0-3 + a0 (5 reads) ----
      asm volatile("s_waitcnt lgkmcnt(3)" ::: "memory");
      __builtin_amdgcn_sched_barrier(0);
      if (PASS == 2) {  // image is the shared N-side in pass 2
        if (dwc == -1) bfr[0] = killlo ? z8 : bfr[0];
        if (dwc == 1) bfr[3] = killhi ? z8 : bfr[3];
      } else {
        if (dwc == -1) afr[0] = killlo ? z8 : afr[0];
      }
      __builtin_amdgcn_s_setprio(1);
#pragma unroll
      for (int j = 0; j < 4; ++j)
        acc[0][j] = __builtin_amdgcn_mfma_f32_16x16x32_bf16(afr[0], bfr[j], acc[0][j], 0, 0, 0);
      __builtin_amdgcn_sched_barrier(0);

      // stage tile kk+2 (issues under MFMA shadow); bump image base at cib cross
      {
        if (s == 7) {
          aCur[0] += 262144;
          aCur[1] += 262144;
        }
        const bool dmy = (c9 == 7) && (s >= 7);  // tn = 9*c9+s+2 >= 72
        stage((s + 2) % 3, (s + 2) % 9, dmy);
      }
      __builtin_amdgcn_sched_barrier(0);

      // ---- cluster 1 ----
      asm volatile("s_waitcnt lgkmcnt(2)" ::: "memory");
      __builtin_amdgcn_sched_barrier(0);
#pragma unroll
      for (int j = 0; j < 4; ++j)
        acc[1][j] = __builtin_amdgcn_mfma_f32_16x16x32_bf16(afr[1], bfr[j], acc[1][j], 0, 0, 0);
      __builtin_amdgcn_sched_barrier(0);

      // ---- cluster 2 ----
      asm volatile("s_waitcnt lgkmcnt(1)" ::: "memory");
      __builtin_amdgcn_sched_barrier(0);
#pragma unroll
      for (int j = 0; j < 4; ++j)
        acc[2][j] = __builtin_amdgcn_mfma_f32_16x16x32_bf16(afr[2], bfr[j], acc[2][j], 0, 0, 0);
      __builtin_amdgcn_sched_barrier(0);

      // ---- cluster 3 ----
      asm volatile("s_waitcnt lgkmcnt(0)" ::: "memory");
      __builtin_amdgcn_sched_barrier(0);
      if (PASS == 1 && dwc == 1) afr[3] = killhi ? z8 : afr[3];
#pragma unroll
      for (int j = 0; j < 4; ++j)
        acc[3][j] = __builtin_amdgcn_mfma_f32_16x16x32_bf16(afr[3], bfr[j], acc[3][j], 0, 0, 0);
      __builtin_amdgcn_s_setprio(0);
      __builtin_amdgcn_sched_barrier(0);
    }
  }
  // drain tail dummy LDS-DMA before epilogue/endpgm
  asm volatile("s_waitcnt vmcnt(0)" ::: "memory");
  __builtin_amdgcn_sched_barrier(0);

  const int lg = lane >> 4;
  const int ln = lane & 15;
  if (PASS == 1) {
    __hip_bfloat16* ho = (__hip_bfloat16*)outp;  // ht2 layout [b][cib][pix][32]
#pragma unroll
    for (int i = 0; i < 4; ++i)
#pragma unroll
      for (int j = 0; j < 4; ++j)
#pragma unroll
        for (int r = 0; r < 4; ++r) {
          int pixel = pbase + (wm << 6) + (i << 4) + (lg << 2) + r;
          int co = (ct << 7) + (wn << 6) + (j << 4) + ln;
          float v = acc[i][j][r];
          v = v > 0.f ? v : 0.f;
          ho[((size_t)(b * 8 + (co >> 5)) << 17) + ((size_t)pixel << 5) + (co & 31)] =
              __float2bfloat16(v);
        }
  } else {
    float* oo = (float*)outp;
#pragma unroll
    for (int i = 0; i < 4; ++i)
#pragma unroll
      for (int j = 0; j < 4; ++j)
#pragma unroll
        for (int r = 0; r < 4; ++r) {
          int co = (ct << 7) + (wm << 6) + (i << 4) + (lg << 2) + r;
          int pixel = pbase + (wn << 6) + (j << 4) + ln;
          size_t idx = ((size_t)(b * NC + co) << 12) + pixel;
          float v = acc[i][j][r] + xres[idx];
          oo[idx] = v > 0.f ? v : 0.f;
        }
  }
}

extern "C" void kernel_launch(void* const* d_in, const int* in_sizes, int n_in,
                              void* d_out, int out_size, void* d_ws, size_t ws_size,
                              hipStream_t stream) {
  const float* x = (const float*)d_in[0];
  const float* k1 = (const float*)d_in[1];
  const float* k2 = (const float*)d_in[2];

  const size_t xtsz = (size_t)NB * 8 * NHW * 32;       // 16.78M elems (33.55 MB)
  const size_t ktsz = (size_t)NB * 2 * NT * 128 * 32;  // 9.44M elems (18.87 MB)
  char* w = (char*)d_ws;
  __hip_bfloat16* xt2 = (__hip_bfloat16*)(w + 256);
  __hip_bfloat16* ht2 = xt2 + xtsz;
  __hip_bfloat16* kt2a = ht2 + xtsz;

  const size_t needA = 256 + 4 * xtsz + 4 * ktsz + 8192;  // dual-kt layout bytes
  if (ws_size >= needA) {
    // big-ws layout: xt2 | ht2 | kt2a | kt2b | zp — single fused prep launch
    __hip_bfloat16* kt2b = kt2a + ktsz;
    float* zp = (float*)(kt2b + ktsz);
    prep_all<<<dim3(12288), 256, 0, stream>>>(x, xt2, zp, k1, kt2a, k2, kt2b);
    conv_gemm<1><<<dim3(1024), 256, 0, stream>>>(xt2, kt2a, nullptr,
                                                 (const __hip_bfloat16*)zp, (void*)ht2);
    conv_gemm<2><<<dim3(1024), 256, 0, stream>>>(ht2, kt2b, x,
                                                 (const __hip_bfloat16*)zp, d_out);
  } else {
    // fallback: reuse kt buffer (round-16 5-launch sequence)
    float* zp = (float*)(kt2a + ktsz);
    prep_xt2<<<dim3(4096), 256, 0, stream>>>(x, xt2, zp);
    prep_kt2<<<dim3(NB * NC), 256, 0, stream>>>(k1, kt2a);
    conv_gemm<1><<<dim3(1024), 256, 0, stream>>>(xt2, kt2a, nullptr,
                                                 (const __hip_bfloat16*)zp, (void*)ht2);
    prep_kt2<<<dim3(NB * NC), 256, 0, stream>>>(k2, kt2a);
    conv_gemm<2><<<dim3(1024), 256, 0, stream>>>(ht2, kt2a, x,
                                                 (const __hip_bfloat16*)zp, d_out);
  }
}